// Round 13
// baseline (136.301 us; speedup 1.0000x reference)
//
#include <hip/hip_runtime.h>
#include <math.h>

// Problem constants: B=64, D=512, H=W=32 -> N=1024, NH=8, DH=64
#define BATCH 64
#define DCH   512
#define NPOS  1024
#define NH    8
#define CSPL  16   // k_dots: c-chunks of 32
#define PVCH  32   // k_pv:   c-chunks of 16

// ---------------------------------------------------------------------------
// K1 (prep): blocks 0-1: wqT[c*8+h] = 0.125 * sum_d q[h,d]*Wkv[c,h*64+d]
//            blocks 2-5: bias[h*1024+n] = 0.125*(q.pe[n] + q.bkv)
// ---------------------------------------------------------------------------
__global__ __launch_bounds__(256) void k_prep(const float* __restrict__ q,
                                              const float* __restrict__ Wkv,
                                              const float* __restrict__ bkv,
                                              float* __restrict__ wqT,
                                              float* __restrict__ bias) {
    int blk = blockIdx.x;
    if (blk < 2) {
        int c = blk * 256 + threadIdx.x;
        const float4* wrow = (const float4*)(Wkv + (size_t)c * (2 * DCH));
        const float4* q4   = (const float4*)q;
        #pragma unroll
        for (int h = 0; h < NH; ++h) {
            float s = 0.f;
            #pragma unroll
            for (int d4 = 0; d4 < 16; ++d4) {
                float4 a = q4[h * 16 + d4];
                float4 w = wrow[h * 16 + d4];
                s = fmaf(a.x, w.x, fmaf(a.y, w.y, fmaf(a.z, w.z, fmaf(a.w, w.w, s))));
            }
            wqT[c * NH + h] = 0.125f * s;
        }
    } else {
        int n = (blk - 2) * 256 + threadIdx.x;
        float pq[NH];
        #pragma unroll
        for (int h = 0; h < NH; ++h) pq[h] = 0.f;
        const float kfac2 = -13.2877123795494f / 64.f;   // -log2(10000)/64
        for (int i = 0; i < 32; ++i) {
            float dt = exp2f((float)(2 * i) * kfac2);
            float ang = (float)n * dt;
            float sn, cs;
            sincosf(ang, &sn, &cs);
            #pragma unroll
            for (int h = 0; h < NH; ++h)
                pq[h] = fmaf(q[h * 64 + 2 * i], sn,
                        fmaf(q[h * 64 + 2 * i + 1], cs, pq[h]));
        }
        #pragma unroll
        for (int h = 0; h < NH; ++h) {
            float bq = 0.f;
            #pragma unroll 8
            for (int d = 0; d < 64; ++d)
                bq = fmaf(q[h * 64 + d], bkv[h * 64 + d], bq);
            bias[h * NPOS + n] = 0.125f * (pq[h] + bq);
        }
    }
}

// ---------------------------------------------------------------------------
// K2 (dots): CONTIGUOUS x streamer. grid (CSPL=16, B) = 1024 blocks, 512 thr.
// Block reads x[b, cs*32:(cs+1)*32, :] = 128 KB fully sequentially:
// thread t owns n-quad nq = t&255 (fixed), c-phase ph = t>>8; iter i reads
// row c = cs*32 + 2i + ph at its n-quad -> block covers 8 KB per iter in
// perfect address order. Weights are wave-uniform (readfirstlane -> s_load).
// LDS pair-reduce (ph1 -> ph0), coalesced 32 KB partial write.
// ---------------------------------------------------------------------------
__global__ __launch_bounds__(512) void k_dots(const float* __restrict__ x,
                                              const float* __restrict__ wqT,
                                              float* __restrict__ pdots) {
    __shared__ float sacc[NH][NPOS];   // 32 KB: ph1 partials [h][nq*4+e]
    int b = blockIdx.y, cs = blockIdx.x;
    int t = threadIdx.x;
    int nq = t & 255;
    int ph = t >> 8;

    const float4* xp = (const float4*)(x + ((size_t)b * DCH + cs * 32) * NPOS) + nq;
    const float* wr = wqT + (cs * 32) * NH;

    float acc[NH][4];
    #pragma unroll
    for (int h = 0; h < NH; ++h)
        #pragma unroll
        for (int e = 0; e < 4; ++e) acc[h][e] = 0.f;

    #pragma unroll
    for (int i = 0; i < 16; ++i) {
        int cl = 2 * i + ph;                 // wave-uniform
        float4 xv = xp[cl * 256];
        int cb = __builtin_amdgcn_readfirstlane(cl) * NH;
        float wv[8];
        *(float4*)&wv[0] = *(const float4*)(wr + cb);
        *(float4*)&wv[4] = *(const float4*)(wr + cb + 4);
        #pragma unroll
        for (int h = 0; h < NH; ++h) {
            acc[h][0] = fmaf(xv.x, wv[h], acc[h][0]);
            acc[h][1] = fmaf(xv.y, wv[h], acc[h][1]);
            acc[h][2] = fmaf(xv.z, wv[h], acc[h][2]);
            acc[h][3] = fmaf(xv.w, wv[h], acc[h][3]);
        }
    }

    if (ph == 1) {
        #pragma unroll
        for (int h = 0; h < NH; ++h)
            *(float4*)&sacc[h][nq * 4] =
                make_float4(acc[h][0], acc[h][1], acc[h][2], acc[h][3]);
    }
    __syncthreads();
    if (ph == 0) {
        size_t obase = ((size_t)cs * BATCH + b) * (NH * NPOS);
        #pragma unroll
        for (int h = 0; h < NH; ++h) {
            float4 s4 = *(const float4*)&sacc[h][nq * 4];
            float4 o;
            o.x = acc[h][0] + s4.x;
            o.y = acc[h][1] + s4.y;
            o.z = acc[h][2] + s4.z;
            o.w = acc[h][3] + s4.w;
            *(float4*)(pdots + obase + (size_t)h * NPOS + nq * 4) = o;
        }
    }
}

// ---------------------------------------------------------------------------
// K3 (dsoft): reduce 16 partials + bias, softmax, write normalized attn.
// grid (B*NH) = 512 blocks, 256 thr (4 waves). Thread owns n-quad t.
// ---------------------------------------------------------------------------
__global__ __launch_bounds__(256) void k_dsoft(const float* __restrict__ pdots,
                                               const float* __restrict__ bias,
                                               float* __restrict__ attn) {
    __shared__ float red[2][4];
    int blk = blockIdx.x;
    int b = blk >> 3, h = blk & 7;
    int t = threadIdx.x, w = t >> 6, lane = t & 63;

    float4 v = *(const float4*)(bias + (size_t)h * NPOS + t * 4);
    #pragma unroll
    for (int cs = 0; cs < CSPL; ++cs) {
        float4 p = *(const float4*)(pdots +
            (((size_t)cs * BATCH + b) * NH + h) * NPOS + t * 4);
        v.x += p.x; v.y += p.y; v.z += p.z; v.w += p.w;
    }

    float m = fmaxf(fmaxf(v.x, v.y), fmaxf(v.z, v.w));
    #pragma unroll
    for (int o = 32; o; o >>= 1) m = fmaxf(m, __shfl_xor(m, o));
    if (lane == 0) red[0][w] = m;
    __syncthreads();
    float M = fmaxf(fmaxf(red[0][0], red[0][1]), fmaxf(red[0][2], red[0][3]));

    v.x = expf(v.x - M); v.y = expf(v.y - M);
    v.z = expf(v.z - M); v.w = expf(v.w - M);
    float z = v.x + v.y + v.z + v.w;
    #pragma unroll
    for (int o = 32; o; o >>= 1) z += __shfl_xor(z, o);
    if (lane == 0) red[1][w] = z;
    __syncthreads();
    float Z = red[1][0] + red[1][1] + red[1][2] + red[1][3];
    float inv = 1.f / Z;
    v.x *= inv; v.y *= inv; v.z *= inv; v.w *= inv;
    *(float4*)(attn + ((size_t)b * NH + h) * NPOS + t * 4) = v;
}

// ---------------------------------------------------------------------------
// K4 (pv): a[b,h,c] = sum_n attn*x. grid (PVCH=32, B) = 2048 blocks, 512 thr.
// Block stages x[b, cs*16:(cs+1)*16, :] = 64 KB CONTIGUOUSLY into LDS
// (conflict-free b128 writes/reads), attn from L2; wave w owns c = 2w+{0,1};
// in-wave-only butterfly reduce; writes final a directly (no combine pass).
// ---------------------------------------------------------------------------
__global__ __launch_bounds__(512) void k_pv(const float* __restrict__ x,
                                            const float* __restrict__ attn,
                                            float* __restrict__ abuf) {
    __shared__ float tile[16 * NPOS];   // 64 KB
    int b = blockIdx.y, cs = blockIdx.x;
    int t = threadIdx.x, w = t >> 6, lane = t & 63;

    const float4* xp = (const float4*)(x + ((size_t)b * DCH + cs * 16) * NPOS);
    float4* tp = (float4*)tile;
    #pragma unroll
    for (int i = 0; i < 8; ++i) tp[t + i * 512] = xp[t + i * 512];
    __syncthreads();

    float con[2][NH];
    #pragma unroll
    for (int r = 0; r < 2; ++r)
        #pragma unroll
        for (int h = 0; h < NH; ++h) con[r][h] = 0.f;

    #pragma unroll
    for (int j = 0; j < 4; ++j) {
        float4 pj[NH];
        #pragma unroll
        for (int h = 0; h < NH; ++h)
            pj[h] = *(const float4*)(attn + ((size_t)b * NH + h) * NPOS
                                     + j * 256 + lane * 4);
        #pragma unroll
        for (int r = 0; r < 2; ++r) {
            float4 xv = *(const float4*)&tile[(2 * w + r) * NPOS + j * 256 + lane * 4];
            #pragma unroll
            for (int h = 0; h < NH; ++h)
                con[r][h] = fmaf(xv.x, pj[h].x, fmaf(xv.y, pj[h].y,
                            fmaf(xv.z, pj[h].z, fmaf(xv.w, pj[h].w, con[r][h]))));
        }
    }

    #pragma unroll
    for (int r = 0; r < 2; ++r)
        #pragma unroll
        for (int h = 0; h < NH; ++h) {
            float v = con[r][h];
            v += __shfl_xor(v, 1);
            v += __shfl_xor(v, 2);
            v += __shfl_xor(v, 4);
            v += __shfl_xor(v, 8);
            v += __shfl_xor(v, 16);
            v += __shfl_xor(v, 32);
            if (lane == 0)
                abuf[((size_t)b * NH + h) * DCH + cs * 16 + 2 * w + r] = v;
        }
}

// ---------------------------------------------------------------------------
// K5 (comb): out[b,hd] = bkv[512+hd] + sum_c a[b,h,c]*Wkv[c,512+hd]
// grid (B, 2), 512 thr. a staged in LDS; Wkv columns from L2.
// ---------------------------------------------------------------------------
__global__ __launch_bounds__(512) void k_comb(const float* __restrict__ abuf,
                                              const float* __restrict__ Wkv,
                                              const float* __restrict__ bkv,
                                              float* __restrict__ out) {
    __shared__ float as[4 * DCH];    // 8 KB: this half's 4 heads
    __shared__ float red[2][256];
    int b = blockIdx.x, half = blockIdx.y, t = threadIdx.x;

    ((float4*)as)[t] =
        ((const float4*)(abuf + (size_t)b * NH * DCH + (size_t)half * 4 * DCH))[t];
    __syncthreads();

    int o  = t & 255;
    int cp = t >> 8;
    int hd = half * 256 + o;
    const float* wp  = Wkv + DCH + hd;
    const float* apr = as + (o >> 6) * DCH;
    float a0 = 0.f, a1 = 0.f, a2 = 0.f, a3 = 0.f;
    int cbeg = cp * 256;
    #pragma unroll 4
    for (int c = cbeg; c < cbeg + 256; c += 4) {
        a0 = fmaf(apr[c],     wp[(size_t)c * (2 * DCH)],       a0);
        a1 = fmaf(apr[c + 1], wp[(size_t)(c + 1) * (2 * DCH)], a1);
        a2 = fmaf(apr[c + 2], wp[(size_t)(c + 2) * (2 * DCH)], a2);
        a3 = fmaf(apr[c + 3], wp[(size_t)(c + 3) * (2 * DCH)], a3);
    }
    red[cp][o] = (a0 + a1) + (a2 + a3);
    __syncthreads();
    if (t < 256) {
        int hd2 = half * 256 + t;
        out[(size_t)b * DCH + hd2] = bkv[DCH + hd2] + red[0][t] + red[1][t];
    }
}

// ---------------------------------------------------------------------------
extern "C" void kernel_launch(void* const* d_in, const int* in_sizes, int n_in,
                              void* d_out, int out_size, void* d_ws, size_t ws_size,
                              hipStream_t stream) {
    const float* x   = (const float*)d_in[0];   // (64, 512, 32, 32)
    const float* q   = (const float*)d_in[1];   // (1, 8, 1, 64)
    const float* Wkv = (const float*)d_in[2];   // (512, 1024)
    const float* bkv = (const float*)d_in[3];   // (1024,)
    float* out = (float*)d_out;                 // (64, 512)

    float* ws    = (float*)d_ws;
    float* wqT   = ws;                                          // 4 K floats
    float* bias  = wqT + DCH * NH;                              // 8 K
    float* pdots = bias + NH * NPOS;                            // 16*64*8*1024 = 32 MB
    float* attn  = pdots + (size_t)CSPL * BATCH * NH * NPOS;    // 2 MB
    float* abuf  = attn + (size_t)BATCH * NH * NPOS;            // 1 MB

    hipLaunchKernelGGL(k_prep,  dim3(6),            dim3(256), 0, stream, q, Wkv, bkv, wqT, bias);
    hipLaunchKernelGGL(k_dots,  dim3(CSPL, BATCH),  dim3(512), 0, stream, x, wqT, pdots);
    hipLaunchKernelGGL(k_dsoft, dim3(BATCH * NH),   dim3(256), 0, stream, pdots, bias, attn);
    hipLaunchKernelGGL(k_pv,    dim3(PVCH, BATCH),  dim3(512), 0, stream, x, attn, abuf);
    hipLaunchKernelGGL(k_comb,  dim3(BATCH, 2),     dim3(512), 0, stream, abuf, Wkv, bkv, out);
}